// Round 10
// baseline (491.051 us; speedup 1.0000x reference)
//
#include <hip/hip_runtime.h>
#include <hip/hip_bf16.h>

// PMField R10: shrink the live set -- z state moves to wave-private LDS.
// R7/R8/R9 showed the schedule's combined live set (~300 regs incl z[32],
// g/gx accum[40], zf[16], pipeline wf[16]) can't fit 2 waves/SIMD no matter
// what the allocator is told (256,1)->1 wave; (256,2)/num_vgpr->spill).
// Fixes:
//  - z fp32 state in wave-private LDS planes zP[w][Mt*2+Nt][lane] (f32x4,
//    lane-linear = conflict-free, no padding): streamed at step edges only.
//  - G-pipeline double-buffer dropped (2nd resident wave now hides the
//    ds write->read latency): sWF 16 KB single buffer.
//  - LDS = 32(sA) + 16(sWF) + 32(zP) = 80 KB -> exactly 2 blocks/CU.
//  - __launch_bounds__(256,2): arch cap 128; without z/pipeline the arch
//    live set is ~110 -> no spill expected (check: FETCH_SIZE ~17 MB).
// Math identical to R9 (nacc/sw via augmented G-tile; z fp32 throughout).
// Layouts (HW-verified R4-R9): C/D col=lane&15,row=q*4+r; A[m=lane&15][k=q*8+j];
// B = transpose-dual; w/z->B-frag scatter:
//   cw=16Mt+4q+r -> plane Kt=Mt>>1, lane m16+16*((2Mt+(q>>1))&3), uint 2(q&1)

#define STEPS 8
#define DTB   0.15f
#define EPSF  1e-4f

typedef short bf16x8 __attribute__((ext_vector_type(8)));
typedef float f32x4  __attribute__((ext_vector_type(4)));
union FragU { int4 i; bf16x8 h; };
union PkU  { __hip_bfloat162 b; unsigned u; };

__device__ __forceinline__ unsigned bfp(float lo, float hi) { // v_cvt_pk_bf16_f32
    PkU p; p.b = __float22bfloat162_rn(make_float2(lo, hi));
    return p.u;
}
__device__ __forceinline__ float med3(float x, float lo, float hi) {
    return __builtin_amdgcn_fmed3f(x, lo, hi);
}

// d_ws layout:
//   int4 [0,    2048)  S-planes: ((c*4+Mt)*2+h)*64+lane = bf16x8 of -2C[center][dims]
//   int4 [2048, 4608)  G-planes: ((Mt*4+c)*2+h)*64+lane, Mt 0..4
//                      Mt<4: bf16x8 of C^T[dim][centers]
//                      Mt=4: row0(=dim 64)=ones, row1(=dim 65)=cn2[centers], rest 0
//   f32  ws[18432+t]   cn2[t]   (t in [0,256))
//   f32  ws[18688+t]   mu[t]
__global__ void pm_prep(const float* __restrict__ centers,
                        const float* __restrict__ mus,
                        unsigned* __restrict__ ws) {
    const int gtid = blockIdx.x * 256 + threadIdx.x;
    if (gtid < 2048) {                       // S-plane frags
        const int c = gtid >> 9, Mt = (gtid >> 7) & 3, h = (gtid >> 6) & 1;
        const int L = gtid & 63, m16 = L & 15, q = L >> 4;
        const float* row = centers + (size_t)(64 * c + 16 * Mt + m16) * 64 + 32 * h + 8 * q;
        uint4 u;
        u.x = bfp(-2.f * row[0], -2.f * row[1]);
        u.y = bfp(-2.f * row[2], -2.f * row[3]);
        u.z = bfp(-2.f * row[4], -2.f * row[5]);
        u.w = bfp(-2.f * row[6], -2.f * row[7]);
        ((uint4*)ws)[gtid] = u;
    } else if (gtid < 4608) {                // G-plane frags
        const int i = gtid - 2048;
        const int Mt = i >> 9, c = (i >> 7) & 3, h = (i >> 6) & 1;
        const int L = i & 63, m16 = L & 15, q = L >> 4;
        uint4 u;
        if (Mt < 4) {                        // C^T rows = dims
            const float* base = centers + (size_t)(64 * c + 32 * h + 8 * q) * 64 + 16 * Mt + m16;
            u.x = bfp(base[0],   base[64]);
            u.y = bfp(base[128], base[192]);
            u.z = bfp(base[256], base[320]);
            u.w = bfp(base[384], base[448]);
        } else if (m16 == 0) {               // row 64: ones
            u.x = u.y = u.z = u.w = 0x3F803F80u;
        } else if (m16 == 1) {               // row 65: cn2[center]
            float c2[8];
#pragma unroll
            for (int j = 0; j < 8; ++j) {
                const float* r = centers + (size_t)(64 * c + 32 * h + 8 * q + j) * 64;
                float a0 = 0.f, a1 = 0.f, a2 = 0.f, a3 = 0.f;
#pragma unroll
                for (int d = 0; d < 64; d += 4) {
                    a0 = fmaf(r[d],     r[d],     a0);
                    a1 = fmaf(r[d + 1], r[d + 1], a1);
                    a2 = fmaf(r[d + 2], r[d + 2], a2);
                    a3 = fmaf(r[d + 3], r[d + 3], a3);
                }
                c2[j] = (a0 + a1) + (a2 + a3);
            }
            u.x = bfp(c2[0], c2[1]); u.y = bfp(c2[2], c2[3]);
            u.z = bfp(c2[4], c2[5]); u.w = bfp(c2[6], c2[7]);
        } else {                             // rows 66-79: zero
            u.x = u.y = u.z = u.w = 0u;
        }
        ((uint4*)ws)[2048 + i] = u;
    } else if (gtid < 4864) {                // cn2 / mu (fp32 tables)
        const int t = gtid - 4608;
        const float* r = centers + (size_t)t * 64;
        float a0 = 0.f, a1 = 0.f, a2 = 0.f, a3 = 0.f;
#pragma unroll
        for (int d = 0; d < 64; d += 4) {
            a0 = fmaf(r[d],     r[d],     a0);
            a1 = fmaf(r[d + 1], r[d + 1], a1);
            a2 = fmaf(r[d + 2], r[d + 2], a2);
            a3 = fmaf(r[d + 3], r[d + 3], a3);
        }
        ((float*)ws)[18432 + t] = (a0 + a1) + (a2 + a3);
        ((float*)ws)[18688 + t] = mus[t];
    }
}

__global__ __launch_bounds__(256, 2)
void pm_main(const float* __restrict__ z_in,
             const unsigned* __restrict__ ws,
             float* __restrict__ z_out) {
    __shared__ int4  sA[2048];          // 32 KB: S-plane frags, block-shared
    __shared__ int4  sWF[4][4][64];     // 16 KB: [wave][plane Kt*2+Nt][lane], single buf
    __shared__ f32x4 zP[4][8][64];      // 32 KB: wave-private fp32 z planes [w][Mt*2+Nt][lane]

    const int4* wsA  = (const int4*)ws;
    const int4* wsG  = wsA + 2048;
    const float* wsC = (const float*)ws + 18432;
    const float* wsU = (const float*)ws + 18688;

    const int tid  = threadIdx.x;
    const int lane = tid & 63;
    const int w    = tid >> 6;
    const int m16  = lane & 15;
    const int q    = lane >> 4;

    // copy S planes to LDS (lane-linear, coalesced, conflict-free)
#pragma unroll
    for (int i = 0; i < 8; ++i) sA[i * 256 + tid] = wsA[i * 256 + tid];
    __syncthreads();

    const int pbase = blockIdx.x * 128;   // 128 particles/block, 32/wave

    // ---- load z (C/D-layout global reads) into wave-private LDS planes ----
#pragma unroll
    for (int Mt = 0; Mt < 4; ++Mt)
#pragma unroll
        for (int Nt = 0; Nt < 2; ++Nt)
            zP[w][Mt * 2 + Nt][lane] =
                *(const f32x4*)(z_in + (size_t)(pbase + 32 * w + m16 + 16 * Nt) * 64
                                + 16 * Mt + 4 * q);

    unsigned* wp = (unsigned*)&sWF[w][0][0];   // wave-private, 1024 uints

#pragma unroll 1
    for (int s = 0; s < STEPS; ++s) {
        // ---- step edge: zz accumulate + z->B-frag scatter (stream one plane at a time) ----
        float zze[2] = {0.f, 0.f};
#pragma unroll
        for (int Mt = 0; Mt < 4; ++Mt) {
            const int Kt = Mt >> 1;
            const int qt = (2 * Mt + (q >> 1)) & 3;
#pragma unroll
            for (int Nt = 0; Nt < 2; ++Nt) {
                const f32x4 zv = zP[w][Mt * 2 + Nt][lane];
#pragma unroll
                for (int r = 0; r < 4; ++r) zze[Nt] = fmaf(zv[r], zv[r], zze[Nt]);
                const int pos = ((Kt * 2 + Nt) * 64 + m16 + 16 * qt) * 4 + 2 * (q & 1);
                *(uint2*)(wp + pos) = make_uint2(bfp(zv[0], zv[1]), bfp(zv[2], zv[3]));
            }
        }
#pragma unroll
        for (int Nt = 0; Nt < 2; ++Nt) {
            float a = zze[Nt];
            a += __shfl_xor(a, 16, 64);
            a += __shfl_xor(a, 32, 64);
            zze[Nt] = a + EPSF;
        }

        FragU zf[2][2];
#pragma unroll
        for (int Kt = 0; Kt < 2; ++Kt)
#pragma unroll
            for (int Nt = 0; Nt < 2; ++Nt)
                zf[Kt][Nt].i = sWF[w][Kt * 2 + Nt][lane];   // lane-linear read

        f32x4 g[4][2];
        f32x4 gx[2];                         // augmented tile rows 64(ones),65(cn2)
#pragma unroll
        for (int Mt = 0; Mt < 4; ++Mt)
#pragma unroll
            for (int Nt = 0; Nt < 2; ++Nt) g[Mt][Nt] = (f32x4){0.f, 0.f, 0.f, 0.f};
        gx[0] = (f32x4){0.f, 0.f, 0.f, 0.f};
        gx[1] = gx[0];

#pragma unroll
        for (int c = 0; c < 4; ++c) {          // 4 chunks x 64 centers
            // ---- S-phase, fused per Mt; w -> sWF planes (overwrites z-frags, zf in regs) ----
#pragma unroll
            for (int Mt = 0; Mt < 4; ++Mt) {
                FragU a0, a1;
                a0.i = sA[((c * 4 + Mt) * 2 + 0) * 64 + lane];
                a1.i = sA[((c * 4 + Mt) * 2 + 1) * 64 + lane];
                f32x4 S[2];
#pragma unroll
                for (int Nt = 0; Nt < 2; ++Nt) {
                    f32x4 acc = (f32x4){0.f, 0.f, 0.f, 0.f};
                    acc = __builtin_amdgcn_mfma_f32_16x16x32_bf16(a0.h, zf[0][Nt].h, acc, 0, 0, 0);
                    acc = __builtin_amdgcn_mfma_f32_16x16x32_bf16(a1.h, zf[1][Nt].h, acc, 0, 0, 0);
                    S[Nt] = acc;   // S = -2*dot; row = center 64c+16Mt+4q+r, col = particle
                }

                const f32x4 cn2v = *(const f32x4*)(wsC + 64 * c + 16 * Mt + 4 * q);
                const f32x4 muv  = *(const f32x4*)(wsU + 64 * c + 16 * Mt + 4 * q);
                float wv[2][4];
#pragma unroll
                for (int r = 0; r < 4; ++r)
#pragma unroll
                    for (int Nt = 0; Nt < 2; ++Nt) {
                        float r2   = fmaxf(S[Nt][r] + (zze[Nt] + cn2v[r]), EPSF);
                        float rin  = __builtin_amdgcn_rsqf(r2);
                        wv[Nt][r]  = muv[r] * (rin * rin * rin);   // mu / r^3
                    }
                const int Kt = Mt >> 1;
                const int qt = (2 * Mt + (q >> 1)) & 3;
#pragma unroll
                for (int Nt = 0; Nt < 2; ++Nt) {
                    const int pos = ((Kt * 2 + Nt) * 64 + m16 + 16 * qt) * 4 + 2 * (q & 1);
                    *(uint2*)(wp + pos) = make_uint2(bfp(wv[Nt][0], wv[Nt][1]),
                                                     bfp(wv[Nt][2], wv[Nt][3]));
                }
            }

            // ---- G-phase same chunk (2nd resident wave hides ds round-trip) ----
            FragU wf[2][2];
#pragma unroll
            for (int Kt = 0; Kt < 2; ++Kt)
#pragma unroll
                for (int Nt = 0; Nt < 2; ++Nt)
                    wf[Kt][Nt].i = sWF[w][Kt * 2 + Nt][lane];
#pragma unroll
            for (int Mt = 0; Mt < 5; ++Mt) {
                FragU ga0, ga1;
                ga0.i = wsG[((Mt * 4 + c) * 2 + 0) * 64 + lane];
                ga1.i = wsG[((Mt * 4 + c) * 2 + 1) * 64 + lane];
#pragma unroll
                for (int Nt = 0; Nt < 2; ++Nt) {
                    f32x4 acc = (Mt < 4) ? g[Mt][Nt] : gx[Nt];
                    acc = __builtin_amdgcn_mfma_f32_16x16x32_bf16(ga0.h, wf[0][Nt].h, acc, 0, 0, 0);
                    acc = __builtin_amdgcn_mfma_f32_16x16x32_bf16(ga1.h, wf[1][Nt].h, acc, 0, 0, 0);
                    if (Mt < 4) g[Mt][Nt] = acc; else gx[Nt] = acc;
                }
            }
        }

        // ---- per-particle scalars + z update (stream z planes from LDS) ----
#pragma unroll
        for (int Nt = 0; Nt < 2; ++Nt) {
            const float sw_b  = __shfl(gx[Nt][0], m16, 64);
            const float cns_b = __shfl(gx[Nt][1], m16, 64);
            float zg = 0.f;
#pragma unroll
            for (int Mt = 0; Mt < 4; ++Mt) {
                const f32x4 zv = zP[w][Mt * 2 + Nt][lane];
#pragma unroll
                for (int r = 0; r < 4; ++r) zg = fmaf(zv[r], g[Mt][Nt][r], zg);
            }
            zg += __shfl_xor(zg, 16, 64);
            zg += __shfl_xor(zg, 32, 64);
            const float nacc = fmaf(zze[Nt], sw_b, cns_b) - 2.f * zg;
            const float tco  = DTB * __builtin_amdgcn_rcpf(1.f + nacc);
#pragma unroll
            for (int Mt = 0; Mt < 4; ++Mt) {
                f32x4 zv = zP[w][Mt * 2 + Nt][lane];
#pragma unroll
                for (int r = 0; r < 4; ++r) {
                    const float gd = fmaf(-sw_b, zv[r], g[Mt][Nt][r]);
                    zv[r] = med3(fmaf(tco, gd, zv[r]), -3.f, 3.f);
                }
                zP[w][Mt * 2 + Nt][lane] = zv;
            }
        }
    }

    // ---- epilogue: stream z planes out (direct C/D-layout store) ----
#pragma unroll
    for (int Mt = 0; Mt < 4; ++Mt)
#pragma unroll
        for (int Nt = 0; Nt < 2; ++Nt)
            *(f32x4*)(z_out + (size_t)(pbase + 32 * w + m16 + 16 * Nt) * 64
                      + 16 * Mt + 4 * q) = zP[w][Mt * 2 + Nt][lane];
}

extern "C" void kernel_launch(void* const* d_in, const int* in_sizes, int n_in,
                              void* d_out, int out_size, void* d_ws, size_t ws_size,
                              hipStream_t stream) {
    const float* z       = (const float*)d_in[0];
    const float* centers = (const float*)d_in[1];
    const float* mus     = (const float*)d_in[2];
    float* out           = (float*)d_out;
    unsigned* ws         = (unsigned*)d_ws;

    pm_prep<<<dim3(19), dim3(256), 0, stream>>>(centers, mus, ws);
    // 131072 particles / 128 per block (4 waves x 32) = 1024 blocks
    pm_main<<<dim3(1024), dim3(256), 0, stream>>>(z, ws, out);
}

// Round 11
// 261.473 us; speedup vs baseline: 1.8780x; 1.8780x over previous
//
#include <hip/hip_runtime.h>
#include <hip/hip_bf16.h>

// PMField R11: R9 with amdgpu_num_vgpr REMOVED -- the consolidation round.
// Empirical law from R4-R10: arch cap = 256/min_waves(launch_bounds); this
// schedule's as-compiled live set ~230; caps 128 (R5/R8/R10) and 200 (R9)
// spill 0.45-1.2 GB HBM; only (256,1) w/ greedy 256 is spill-free (R4/R7:
// FETCH ~17 MB). 1 wave/SIMD is the stable point; take it and keep R9's
// three real wins (masked by its spill):
//  - G-phase pipelined one chunk behind S-phase (double-buffered wave-private
//    frag planes): w write->read LDS round-trip hidden under next S-phase.
//  - nacc/sw offloaded to augmented G-tile (row64=ones -> sw, row65=cn2);
//    nacc = -2*(z.g) + (zz+eps)*sw + sum(w*cn2). Exact algebra (r2 clamp
//    never fires: min |z-c|^2 >> eps).
//  - v_cvt_pk_bf16_f32 packs.
// Layouts (HW-verified R4-R10): C/D col=lane&15,row=q*4+r; A[m=lane&15][k=q*8+j];
// B = transpose-dual; w/z->B-frag scatter:
//   cw=16Mt+4q+r -> plane Kt=Mt>>1, lane m16+16*((2Mt+(q>>1))&3), uint 2(q&1)

#define STEPS 8
#define DTB   0.15f
#define EPSF  1e-4f

typedef short bf16x8 __attribute__((ext_vector_type(8)));
typedef float f32x4  __attribute__((ext_vector_type(4)));
union FragU { int4 i; bf16x8 h; };
union PkU  { __hip_bfloat162 b; unsigned u; };

__device__ __forceinline__ unsigned bfp(float lo, float hi) { // v_cvt_pk_bf16_f32
    PkU p; p.b = __float22bfloat162_rn(make_float2(lo, hi));
    return p.u;
}
__device__ __forceinline__ float med3(float x, float lo, float hi) {
    return __builtin_amdgcn_fmed3f(x, lo, hi);
}

// d_ws layout:
//   int4 [0,    2048)  S-planes: ((c*4+Mt)*2+h)*64+lane = bf16x8 of -2C[center][dims]
//   int4 [2048, 4608)  G-planes: ((Mt*4+c)*2+h)*64+lane, Mt 0..4
//                      Mt<4: bf16x8 of C^T[dim][centers]
//                      Mt=4: row0(=dim 64)=ones, row1(=dim 65)=cn2[centers], rest 0
//   f32  ws[18432+t]   cn2[t]   (t in [0,256))
//   f32  ws[18688+t]   mu[t]
__global__ void pm_prep(const float* __restrict__ centers,
                        const float* __restrict__ mus,
                        unsigned* __restrict__ ws) {
    const int gtid = blockIdx.x * 256 + threadIdx.x;
    if (gtid < 2048) {                       // S-plane frags
        const int c = gtid >> 9, Mt = (gtid >> 7) & 3, h = (gtid >> 6) & 1;
        const int L = gtid & 63, m16 = L & 15, q = L >> 4;
        const float* row = centers + (size_t)(64 * c + 16 * Mt + m16) * 64 + 32 * h + 8 * q;
        uint4 u;
        u.x = bfp(-2.f * row[0], -2.f * row[1]);
        u.y = bfp(-2.f * row[2], -2.f * row[3]);
        u.z = bfp(-2.f * row[4], -2.f * row[5]);
        u.w = bfp(-2.f * row[6], -2.f * row[7]);
        ((uint4*)ws)[gtid] = u;
    } else if (gtid < 4608) {                // G-plane frags
        const int i = gtid - 2048;
        const int Mt = i >> 9, c = (i >> 7) & 3, h = (i >> 6) & 1;
        const int L = i & 63, m16 = L & 15, q = L >> 4;
        uint4 u;
        if (Mt < 4) {                        // C^T rows = dims
            const float* base = centers + (size_t)(64 * c + 32 * h + 8 * q) * 64 + 16 * Mt + m16;
            u.x = bfp(base[0],   base[64]);
            u.y = bfp(base[128], base[192]);
            u.z = bfp(base[256], base[320]);
            u.w = bfp(base[384], base[448]);
        } else if (m16 == 0) {               // row 64: ones
            u.x = u.y = u.z = u.w = 0x3F803F80u;
        } else if (m16 == 1) {               // row 65: cn2[center]
            float c2[8];
#pragma unroll
            for (int j = 0; j < 8; ++j) {
                const float* r = centers + (size_t)(64 * c + 32 * h + 8 * q + j) * 64;
                float a0 = 0.f, a1 = 0.f, a2 = 0.f, a3 = 0.f;
#pragma unroll
                for (int d = 0; d < 64; d += 4) {
                    a0 = fmaf(r[d],     r[d],     a0);
                    a1 = fmaf(r[d + 1], r[d + 1], a1);
                    a2 = fmaf(r[d + 2], r[d + 2], a2);
                    a3 = fmaf(r[d + 3], r[d + 3], a3);
                }
                c2[j] = (a0 + a1) + (a2 + a3);
            }
            u.x = bfp(c2[0], c2[1]); u.y = bfp(c2[2], c2[3]);
            u.z = bfp(c2[4], c2[5]); u.w = bfp(c2[6], c2[7]);
        } else {                             // rows 66-79: zero
            u.x = u.y = u.z = u.w = 0u;
        }
        ((uint4*)ws)[2048 + i] = u;
    } else if (gtid < 4864) {                // cn2 / mu (fp32 tables)
        const int t = gtid - 4608;
        const float* r = centers + (size_t)t * 64;
        float a0 = 0.f, a1 = 0.f, a2 = 0.f, a3 = 0.f;
#pragma unroll
        for (int d = 0; d < 64; d += 4) {
            a0 = fmaf(r[d],     r[d],     a0);
            a1 = fmaf(r[d + 1], r[d + 1], a1);
            a2 = fmaf(r[d + 2], r[d + 2], a2);
            a3 = fmaf(r[d + 3], r[d + 3], a3);
        }
        ((float*)ws)[18432 + t] = (a0 + a1) + (a2 + a3);
        ((float*)ws)[18688 + t] = mus[t];
    }
}

__global__ __launch_bounds__(256, 1)
void pm_main(const float* __restrict__ z_in,
             const unsigned* __restrict__ ws,
             float* __restrict__ z_out) {
    __shared__ int4 sA[2048];             // 32 KB: S-plane frags, block-shared
    __shared__ int4 sWF[4][2][4][64];     // 32 KB: [wave][buf][plane][lane]

    const int4* wsA  = (const int4*)ws;
    const int4* wsG  = wsA + 2048;
    const float* wsC = (const float*)ws + 18432;
    const float* wsU = (const float*)ws + 18688;

    const int tid  = threadIdx.x;
    const int lane = tid & 63;
    const int w    = tid >> 6;
    const int m16  = lane & 15;
    const int q    = lane >> 4;

    // copy S planes to LDS (lane-linear, coalesced, conflict-free)
#pragma unroll
    for (int i = 0; i < 8; ++i) sA[i * 256 + tid] = wsA[i * 256 + tid];
    __syncthreads();

    const int pbase = blockIdx.x * 128;   // 128 particles/block, 32/wave

    // z state in C/D layout: lane holds dims {16Mt+4q..+3} x particles {m16, m16+16}
    f32x4 z[4][2];
#pragma unroll
    for (int Mt = 0; Mt < 4; ++Mt)
#pragma unroll
        for (int Nt = 0; Nt < 2; ++Nt)
            z[Mt][Nt] = *(const f32x4*)(z_in + (size_t)(pbase + 32 * w + m16 + 16 * Nt) * 64
                                        + 16 * Mt + 4 * q);

    unsigned* wp = (unsigned*)&sWF[w][0][0][0];   // wave-private, 2 bufs x 1024 uints

#pragma unroll 1
    for (int s = 0; s < STEPS; ++s) {
        // zz per particle (butterfly over q groups), pre-add EPS
        float zze[2];
#pragma unroll
        for (int Nt = 0; Nt < 2; ++Nt) {
            float a = 0.f;
#pragma unroll
            for (int Mt = 0; Mt < 4; ++Mt)
#pragma unroll
                for (int r = 0; r < 4; ++r) a = fmaf(z[Mt][Nt][r], z[Mt][Nt][r], a);
            a += __shfl_xor(a, 16, 64);
            a += __shfl_xor(a, 32, 64);
            zze[Nt] = a + EPSF;
        }

        // z (C/D regs) -> B-frag planes in buf0 (read before chunk0 overwrites)
#pragma unroll
        for (int Mt = 0; Mt < 4; ++Mt) {
            const int Kt = Mt >> 1;
            const int qt = (2 * Mt + (q >> 1)) & 3;
#pragma unroll
            for (int Nt = 0; Nt < 2; ++Nt) {
                const int pos = ((Kt * 2 + Nt) * 64 + m16 + 16 * qt) * 4 + 2 * (q & 1);
                *(uint2*)(wp + pos) = make_uint2(bfp(z[Mt][Nt][0], z[Mt][Nt][1]),
                                                 bfp(z[Mt][Nt][2], z[Mt][Nt][3]));
            }
        }
        FragU zf[2][2];
#pragma unroll
        for (int Kt = 0; Kt < 2; ++Kt)
#pragma unroll
            for (int Nt = 0; Nt < 2; ++Nt)
                zf[Kt][Nt].i = sWF[w][0][Kt * 2 + Nt][lane];   // lane-linear read

        f32x4 g[4][2];
        f32x4 gx[2];                         // augmented tile: rows 64(ones),65(cn2)
#pragma unroll
        for (int Mt = 0; Mt < 4; ++Mt)
#pragma unroll
            for (int Nt = 0; Nt < 2; ++Nt) g[Mt][Nt] = (f32x4){0.f, 0.f, 0.f, 0.f};
        gx[0] = (f32x4){0.f, 0.f, 0.f, 0.f};
        gx[1] = gx[0];

#pragma unroll
        for (int c = 0; c < 4; ++c) {          // 4 chunks x 64 centers
            unsigned* wcur = wp + (c & 1) * 1024;

            // ---- S-phase, fused per Mt; w -> plane buf (c&1) ----
#pragma unroll
            for (int Mt = 0; Mt < 4; ++Mt) {
                FragU a0, a1;
                a0.i = sA[((c * 4 + Mt) * 2 + 0) * 64 + lane];
                a1.i = sA[((c * 4 + Mt) * 2 + 1) * 64 + lane];
                f32x4 S[2];
#pragma unroll
                for (int Nt = 0; Nt < 2; ++Nt) {
                    f32x4 acc = (f32x4){0.f, 0.f, 0.f, 0.f};
                    acc = __builtin_amdgcn_mfma_f32_16x16x32_bf16(a0.h, zf[0][Nt].h, acc, 0, 0, 0);
                    acc = __builtin_amdgcn_mfma_f32_16x16x32_bf16(a1.h, zf[1][Nt].h, acc, 0, 0, 0);
                    S[Nt] = acc;   // S = -2*dot; row = center 64c+16Mt+4q+r, col = particle
                }

                const f32x4 cn2v = *(const f32x4*)(wsC + 64 * c + 16 * Mt + 4 * q);
                const f32x4 muv  = *(const f32x4*)(wsU + 64 * c + 16 * Mt + 4 * q);
                float wv[2][4];
#pragma unroll
                for (int r = 0; r < 4; ++r)
#pragma unroll
                    for (int Nt = 0; Nt < 2; ++Nt) {
                        float r2   = fmaxf(S[Nt][r] + (zze[Nt] + cn2v[r]), EPSF);
                        float rin  = __builtin_amdgcn_rsqf(r2);
                        wv[Nt][r]  = muv[r] * (rin * rin * rin);   // mu / r^3
                    }
                const int Kt = Mt >> 1;
                const int qt = (2 * Mt + (q >> 1)) & 3;
#pragma unroll
                for (int Nt = 0; Nt < 2; ++Nt) {
                    const int pos = ((Kt * 2 + Nt) * 64 + m16 + 16 * qt) * 4 + 2 * (q & 1);
                    *(uint2*)(wcur + pos) = make_uint2(bfp(wv[Nt][0], wv[Nt][1]),
                                                       bfp(wv[Nt][2], wv[Nt][3]));
                }
            }

            // ---- G-phase for PREVIOUS chunk (write->read latency hidden) ----
            if (c > 0) {
                const int cg = c - 1;
                FragU wf[2][2];
#pragma unroll
                for (int Kt = 0; Kt < 2; ++Kt)
#pragma unroll
                    for (int Nt = 0; Nt < 2; ++Nt)
                        wf[Kt][Nt].i = sWF[w][cg & 1][Kt * 2 + Nt][lane];
#pragma unroll
                for (int Mt = 0; Mt < 5; ++Mt) {
                    FragU ga0, ga1;
                    ga0.i = wsG[((Mt * 4 + cg) * 2 + 0) * 64 + lane];
                    ga1.i = wsG[((Mt * 4 + cg) * 2 + 1) * 64 + lane];
#pragma unroll
                    for (int Nt = 0; Nt < 2; ++Nt) {
                        f32x4 acc = (Mt < 4) ? g[Mt][Nt] : gx[Nt];
                        acc = __builtin_amdgcn_mfma_f32_16x16x32_bf16(ga0.h, wf[0][Nt].h, acc, 0, 0, 0);
                        acc = __builtin_amdgcn_mfma_f32_16x16x32_bf16(ga1.h, wf[1][Nt].h, acc, 0, 0, 0);
                        if (Mt < 4) g[Mt][Nt] = acc; else gx[Nt] = acc;
                    }
                }
            }
        }
        // ---- tail: G-phase for chunk 3 ----
        {
            FragU wf[2][2];
#pragma unroll
            for (int Kt = 0; Kt < 2; ++Kt)
#pragma unroll
                for (int Nt = 0; Nt < 2; ++Nt)
                    wf[Kt][Nt].i = sWF[w][1][Kt * 2 + Nt][lane];
#pragma unroll
            for (int Mt = 0; Mt < 5; ++Mt) {
                FragU ga0, ga1;
                ga0.i = wsG[((Mt * 4 + 3) * 2 + 0) * 64 + lane];
                ga1.i = wsG[((Mt * 4 + 3) * 2 + 1) * 64 + lane];
#pragma unroll
                for (int Nt = 0; Nt < 2; ++Nt) {
                    f32x4 acc = (Mt < 4) ? g[Mt][Nt] : gx[Nt];
                    acc = __builtin_amdgcn_mfma_f32_16x16x32_bf16(ga0.h, wf[0][Nt].h, acc, 0, 0, 0);
                    acc = __builtin_amdgcn_mfma_f32_16x16x32_bf16(ga1.h, wf[1][Nt].h, acc, 0, 0, 0);
                    if (Mt < 4) g[Mt][Nt] = acc; else gx[Nt] = acc;
                }
            }
        }

        // ---- per-particle scalars from augmented rows + z.g dot ----
#pragma unroll
        for (int Nt = 0; Nt < 2; ++Nt) {
            const float sw_b  = __shfl(gx[Nt][0], m16, 64);
            const float cns_b = __shfl(gx[Nt][1], m16, 64);
            float zg = 0.f;
#pragma unroll
            for (int Mt = 0; Mt < 4; ++Mt)
#pragma unroll
                for (int r = 0; r < 4; ++r) zg = fmaf(z[Mt][Nt][r], g[Mt][Nt][r], zg);
            zg += __shfl_xor(zg, 16, 64);
            zg += __shfl_xor(zg, 32, 64);
            const float nacc = fmaf(zze[Nt], sw_b, cns_b) - 2.f * zg;
            const float tco  = DTB * __builtin_amdgcn_rcpf(1.f + nacc);
#pragma unroll
            for (int Mt = 0; Mt < 4; ++Mt)
#pragma unroll
                for (int r = 0; r < 4; ++r) {
                    const float gd = fmaf(-sw_b, z[Mt][Nt][r], g[Mt][Nt][r]);
                    z[Mt][Nt][r] = med3(fmaf(tco, gd, z[Mt][Nt][r]), -3.f, 3.f);
                }
        }
    }

    // direct C/D-layout store
#pragma unroll
    for (int Mt = 0; Mt < 4; ++Mt)
#pragma unroll
        for (int Nt = 0; Nt < 2; ++Nt)
            *(f32x4*)(z_out + (size_t)(pbase + 32 * w + m16 + 16 * Nt) * 64
                      + 16 * Mt + 4 * q) = z[Mt][Nt];
}

extern "C" void kernel_launch(void* const* d_in, const int* in_sizes, int n_in,
                              void* d_out, int out_size, void* d_ws, size_t ws_size,
                              hipStream_t stream) {
    const float* z       = (const float*)d_in[0];
    const float* centers = (const float*)d_in[1];
    const float* mus     = (const float*)d_in[2];
    float* out           = (float*)d_out;
    unsigned* ws         = (unsigned*)d_ws;

    pm_prep<<<dim3(19), dim3(256), 0, stream>>>(centers, mus, ws);
    // 131072 particles / 128 per block (4 waves x 32) = 1024 blocks
    pm_main<<<dim3(1024), dim3(256), 0, stream>>>(z, ws, out);
}